// Round 1
// baseline (4509.221 us; speedup 1.0000x reference)
//
#include <hip/hip_runtime.h>

#define NNODES 100000
#define DIM    256
#define NEDGE  300000

// ---------------- degree ----------------
__global__ void deg_kernel(const int* __restrict__ dst, float* __restrict__ deg, int E) {
    int e = blockIdx.x * blockDim.x + threadIdx.x;
    if (e < E) atomicAdd(&deg[dst[e]], 1.0f);
}

__global__ void inv_deg_kernel(float* __restrict__ deg, int n) {
    int i = blockIdx.x * blockDim.x + threadIdx.x;
    if (i < n) deg[i] = 1.0f / fmaxf(deg[i], 1.0f);
}

// ---------------- scatter-add (one wave per edge, float4 per lane) ----------------
__global__ void scatter_kernel(const int* __restrict__ src, const int* __restrict__ dst,
                               const float* __restrict__ x, float* __restrict__ agg, int E) {
    int tid   = blockIdx.x * blockDim.x + threadIdx.x;
    int lane  = tid & 63;
    int wave  = tid >> 6;
    int nwave = (gridDim.x * blockDim.x) >> 6;
    for (int e = wave; e < E; e += nwave) {
        int s = src[e], d = dst[e];
        float4 v = ((const float4*)(x + (size_t)s * DIM))[lane];
        float* o = agg + (size_t)d * DIM + lane * 4;
        atomicAdd(o + 0, v.x);
        atomicAdd(o + 1, v.y);
        atomicAdd(o + 2, v.z);
        atomicAdd(o + 3, v.w);
    }
}

// ---------------- fused SAGE GEMM: out = (agg*inv_deg)@Wl^T + xin@Wr^T + b ----------------
// Virtual A = [agg_norm | xin]  (M x 512), virtual B = [Wl | Wr] (256 x 512), C = A @ B^T
#define BM 64
#define BN 64
#define BK 16

__global__ __launch_bounds__(256) void sage_gemm(
    const float* __restrict__ agg, const float* __restrict__ inv_deg,
    const float* __restrict__ xin,
    const float* __restrict__ Wl, const float* __restrict__ Wr,
    const float* __restrict__ bias,
    float* __restrict__ out, int M, int do_relu)
{
    __shared__ float As[BK][BM + 4];
    __shared__ float Bs[BK][BN + 4];

    const int t    = threadIdx.x;
    const int row0 = blockIdx.x * BM;
    const int col0 = blockIdx.y * BN;
    const int tx   = t & 15;      // 16 cols of threads
    const int ty   = t >> 4;      // 16 rows of threads
    const int lr   = t >> 2;      // loader: row within tile [0,64)
    const int lk   = (t & 3) * 4; // loader: k offset {0,4,8,12}

    float acc[4][4] = {};

    for (int kc = 0; kc < 2 * DIM; kc += BK) {
        // --- stage A tile (transposed into LDS) ---
        {
            int gi = row0 + lr;
            int k  = kc + lk;
            float4 v = make_float4(0.f, 0.f, 0.f, 0.f);
            if (gi < M) {
                if (k < DIM) {
                    v = *(const float4*)(agg + (size_t)gi * DIM + k);
                    float s = inv_deg[gi];
                    v.x *= s; v.y *= s; v.z *= s; v.w *= s;
                } else {
                    v = *(const float4*)(xin + (size_t)gi * DIM + (k - DIM));
                }
            }
            As[lk + 0][lr] = v.x;
            As[lk + 1][lr] = v.y;
            As[lk + 2][lr] = v.z;
            As[lk + 3][lr] = v.w;
        }
        // --- stage B tile (transposed into LDS); col tiles always in-range ---
        {
            int j = col0 + lr;
            int k = kc + lk;
            float4 v;
            if (k < DIM) v = *(const float4*)(Wl + (size_t)j * DIM + k);
            else         v = *(const float4*)(Wr + (size_t)j * DIM + (k - DIM));
            Bs[lk + 0][lr] = v.x;
            Bs[lk + 1][lr] = v.y;
            Bs[lk + 2][lr] = v.z;
            Bs[lk + 3][lr] = v.w;
        }
        __syncthreads();

        #pragma unroll
        for (int kk = 0; kk < BK; kk++) {
            float a[4], b[4];
            #pragma unroll
            for (int ii = 0; ii < 4; ii++) a[ii] = As[kk][ty * 4 + ii];
            #pragma unroll
            for (int jj = 0; jj < 4; jj++) b[jj] = Bs[kk][tx * 4 + jj];
            #pragma unroll
            for (int ii = 0; ii < 4; ii++)
                #pragma unroll
                for (int jj = 0; jj < 4; jj++)
                    acc[ii][jj] = fmaf(a[ii], b[jj], acc[ii][jj]);
        }
        __syncthreads();
    }

    // --- epilogue: bias + optional relu ---
    #pragma unroll
    for (int ii = 0; ii < 4; ii++) {
        int gi = row0 + ty * 4 + ii;
        if (gi >= M) continue;
        #pragma unroll
        for (int jj = 0; jj < 4; jj++) {
            int gj = col0 + tx * 4 + jj;
            float v = acc[ii][jj] + bias[gj];
            if (do_relu) v = fmaxf(v, 0.f);
            out[(size_t)gi * DIM + gj] = v;
        }
    }
}

extern "C" void kernel_launch(void* const* d_in, const int* in_sizes, int n_in,
                              void* d_out, int out_size, void* d_ws, size_t ws_size,
                              hipStream_t stream) {
    const int*   edge = (const int*)d_in[0];
    const int*   src  = edge;
    const int*   dst  = edge + NEDGE;
    const float* x    = (const float*)d_in[1];
    const float* Wl1  = (const float*)d_in[2];
    const float* Wr1  = (const float*)d_in[3];
    const float* b1   = (const float*)d_in[4];
    const float* Wl2  = (const float*)d_in[5];
    const float* Wr2  = (const float*)d_in[6];
    const float* b2   = (const float*)d_in[7];
    const float* Wl3  = (const float*)d_in[8];
    const float* Wr3  = (const float*)d_in[9];
    const float* b3   = (const float*)d_in[10];

    const size_t feat = (size_t)NNODES * DIM;
    float* agg = (float*)d_ws;
    float* h2  = agg + feat;
    float* deg = h2 + feat;
    float* h1  = (float*)d_out;   // layer-1 output lives in d_out, rewritten by layer 3

    // degree (shared across all layers)
    hipMemsetAsync(deg, 0, NNODES * sizeof(float), stream);
    deg_kernel<<<(NEDGE + 255) / 256, 256, 0, stream>>>(dst, deg, NEDGE);
    inv_deg_kernel<<<(NNODES + 255) / 256, 256, 0, stream>>>(deg, NNODES);

    dim3 ggrid((NNODES + BM - 1) / BM, DIM / BN);

    // ---- layer 1: in = x, out = h1 (d_out), relu ----
    hipMemsetAsync(agg, 0, feat * sizeof(float), stream);
    scatter_kernel<<<2048, 256, 0, stream>>>(src, dst, x, agg, NEDGE);
    sage_gemm<<<ggrid, 256, 0, stream>>>(agg, deg, x, Wl1, Wr1, b1, h1, NNODES, 1);

    // ---- layer 2: in = h1, out = h2 (ws), relu ----
    hipMemsetAsync(agg, 0, feat * sizeof(float), stream);
    scatter_kernel<<<2048, 256, 0, stream>>>(src, dst, h1, agg, NEDGE);
    sage_gemm<<<ggrid, 256, 0, stream>>>(agg, deg, h1, Wl2, Wr2, b2, h2, NNODES, 1);

    // ---- layer 3: in = h2, out = d_out, no relu ----
    hipMemsetAsync(agg, 0, feat * sizeof(float), stream);
    scatter_kernel<<<2048, 256, 0, stream>>>(src, dst, h2, agg, NEDGE);
    sage_gemm<<<ggrid, 256, 0, stream>>>(agg, deg, h2, Wl3, Wr3, b3, (float*)d_out, NNODES, 0);
}

// Round 2
// 1708.335 us; speedup vs baseline: 2.6395x; 2.6395x over previous
//
#include <hip/hip_runtime.h>

#define NNODES 100000
#define DIM    256
#define NEDGE  300000

// ================= CSR build (counting sort by dst) =================

__global__ void count_kernel(const int* __restrict__ dst, int* __restrict__ cnt, int E) {
    int e = blockIdx.x * blockDim.x + threadIdx.x;
    if (e < E) atomicAdd(&cnt[dst[e]], 1);
}

// per-block reduce of cnt -> partial[block]
__global__ void scan1(const int* __restrict__ cnt, int* __restrict__ partial, int n) {
    __shared__ int s[256];
    int i = blockIdx.x * 256 + threadIdx.x;
    s[threadIdx.x] = (i < n) ? cnt[i] : 0;
    __syncthreads();
    for (int off = 128; off > 0; off >>= 1) {
        if (threadIdx.x < off) s[threadIdx.x] += s[threadIdx.x + off];
        __syncthreads();
    }
    if (threadIdx.x == 0) partial[blockIdx.x] = s[0];
}

// single-block exclusive scan of partials (nb <= 512)
__global__ void scan2(int* __restrict__ partial, int nb) {
    __shared__ int s[512];
    int t = threadIdx.x;
    int orig = (t < nb) ? partial[t] : 0;
    s[t] = orig;
    __syncthreads();
    for (int off = 1; off < 512; off <<= 1) {
        int v = (t >= off) ? s[t - off] : 0;
        __syncthreads();
        s[t] += v;
        __syncthreads();
    }
    if (t < nb) partial[t] = s[t] - orig;  // exclusive
}

// per-block exclusive scan + block offset -> row_start
__global__ void scan3(const int* __restrict__ cnt, const int* __restrict__ partial,
                      int* __restrict__ row_start, int n) {
    __shared__ int s[256];
    int i = blockIdx.x * 256 + threadIdx.x;
    int v = (i < n) ? cnt[i] : 0;
    s[threadIdx.x] = v;
    __syncthreads();
    for (int off = 1; off < 256; off <<= 1) {
        int t = (threadIdx.x >= off) ? s[threadIdx.x - off] : 0;
        __syncthreads();
        s[threadIdx.x] += t;
        __syncthreads();
    }
    if (i < n) row_start[i] = partial[blockIdx.x] + s[threadIdx.x] - v;
}

__global__ void fill_csr(const int* __restrict__ src, const int* __restrict__ dst,
                         const int* __restrict__ row_start, int* __restrict__ cursor,
                         int* __restrict__ esrc, int E) {
    int e = blockIdx.x * blockDim.x + threadIdx.x;
    if (e < E) {
        int d = dst[e];
        int pos = row_start[d] + atomicAdd(&cursor[d], 1);
        esrc[pos] = src[e];
    }
}

// ================= aggregation: one wave per node, registers, no atomics =================
__global__ __launch_bounds__(256) void aggregate(
    const int* __restrict__ esrc, const int* __restrict__ row_start,
    const int* __restrict__ cnt, const float* __restrict__ x, float* __restrict__ agg)
{
    int node = (blockIdx.x * blockDim.x + threadIdx.x) >> 6;
    int lane = threadIdx.x & 63;
    if (node >= NNODES) return;
    int start = row_start[node];
    int c = cnt[node];
    float4 acc = make_float4(0.f, 0.f, 0.f, 0.f);
    for (int i = 0; i < c; i++) {
        int s = esrc[start + i];
        float4 v = ((const float4*)(x + (size_t)s * DIM))[lane];
        acc.x += v.x; acc.y += v.y; acc.z += v.z; acc.w += v.w;
    }
    float inv = (c > 0) ? 1.0f / (float)c : 0.0f;
    ((float4*)(agg + (size_t)node * DIM))[lane] =
        make_float4(acc.x * inv, acc.y * inv, acc.z * inv, acc.w * inv);
}

// ================= fused SAGE GEMM: out = agg_norm@Wl^T + xin@Wr^T + b =================
#define BM 64
#define BN 64
#define BK 16

__global__ __launch_bounds__(256) void sage_gemm(
    const float* __restrict__ agg,
    const float* __restrict__ xin,
    const float* __restrict__ Wl, const float* __restrict__ Wr,
    const float* __restrict__ bias,
    float* __restrict__ out, int M, int do_relu)
{
    __shared__ float As[BK][BM + 4];
    __shared__ float Bs[BK][BN + 4];

    const int t    = threadIdx.x;
    const int row0 = blockIdx.x * BM;
    const int col0 = blockIdx.y * BN;
    const int tx   = t & 15;
    const int ty   = t >> 4;
    const int lr   = t >> 2;
    const int lk   = (t & 3) * 4;

    float acc[4][4] = {};

    for (int kc = 0; kc < 2 * DIM; kc += BK) {
        {
            int gi = row0 + lr;
            int k  = kc + lk;
            float4 v = make_float4(0.f, 0.f, 0.f, 0.f);
            if (gi < M) {
                if (k < DIM) v = *(const float4*)(agg + (size_t)gi * DIM + k);
                else         v = *(const float4*)(xin + (size_t)gi * DIM + (k - DIM));
            }
            As[lk + 0][lr] = v.x;
            As[lk + 1][lr] = v.y;
            As[lk + 2][lr] = v.z;
            As[lk + 3][lr] = v.w;
        }
        {
            int j = col0 + lr;
            int k = kc + lk;
            float4 v;
            if (k < DIM) v = *(const float4*)(Wl + (size_t)j * DIM + k);
            else         v = *(const float4*)(Wr + (size_t)j * DIM + (k - DIM));
            Bs[lk + 0][lr] = v.x;
            Bs[lk + 1][lr] = v.y;
            Bs[lk + 2][lr] = v.z;
            Bs[lk + 3][lr] = v.w;
        }
        __syncthreads();

        #pragma unroll
        for (int kk = 0; kk < BK; kk++) {
            float a[4], b[4];
            #pragma unroll
            for (int ii = 0; ii < 4; ii++) a[ii] = As[kk][ty * 4 + ii];
            #pragma unroll
            for (int jj = 0; jj < 4; jj++) b[jj] = Bs[kk][tx * 4 + jj];
            #pragma unroll
            for (int ii = 0; ii < 4; ii++)
                #pragma unroll
                for (int jj = 0; jj < 4; jj++)
                    acc[ii][jj] = fmaf(a[ii], b[jj], acc[ii][jj]);
        }
        __syncthreads();
    }

    #pragma unroll
    for (int ii = 0; ii < 4; ii++) {
        int gi = row0 + ty * 4 + ii;
        if (gi >= M) continue;
        #pragma unroll
        for (int jj = 0; jj < 4; jj++) {
            int gj = col0 + tx * 4 + jj;
            float v = acc[ii][jj] + bias[gj];
            if (do_relu) v = fmaxf(v, 0.f);
            out[(size_t)gi * DIM + gj] = v;
        }
    }
}

extern "C" void kernel_launch(void* const* d_in, const int* in_sizes, int n_in,
                              void* d_out, int out_size, void* d_ws, size_t ws_size,
                              hipStream_t stream) {
    const int*   edge = (const int*)d_in[0];
    const int*   src  = edge;
    const int*   dst  = edge + NEDGE;
    const float* x    = (const float*)d_in[1];
    const float* Wl1  = (const float*)d_in[2];
    const float* Wr1  = (const float*)d_in[3];
    const float* b1   = (const float*)d_in[4];
    const float* Wl2  = (const float*)d_in[5];
    const float* Wr2  = (const float*)d_in[6];
    const float* b2   = (const float*)d_in[7];
    const float* Wl3  = (const float*)d_in[8];
    const float* Wr3  = (const float*)d_in[9];
    const float* b3   = (const float*)d_in[10];

    const size_t feat = (size_t)NNODES * DIM;
    float* agg       = (float*)d_ws;
    float* h2        = agg + feat;
    int*   cnt       = (int*)(h2 + feat);
    int*   row_start = cnt + NNODES;
    int*   cursor    = row_start + NNODES;
    int*   partial   = cursor + NNODES;
    int*   esrc      = partial + 512;
    float* h1        = (float*)d_out;   // layer-1 out in d_out; rewritten by layer 3

    const int nScanBlocks = (NNODES + 255) / 256;   // 391

    // ---- CSR build (once; edge structure shared by all 3 layers) ----
    hipMemsetAsync(cnt, 0, NNODES * sizeof(int), stream);
    hipMemsetAsync(cursor, 0, NNODES * sizeof(int), stream);
    count_kernel<<<(NEDGE + 255) / 256, 256, 0, stream>>>(dst, cnt, NEDGE);
    scan1<<<nScanBlocks, 256, 0, stream>>>(cnt, partial, NNODES);
    scan2<<<1, 512, 0, stream>>>(partial, nScanBlocks);
    scan3<<<nScanBlocks, 256, 0, stream>>>(cnt, partial, row_start, NNODES);
    fill_csr<<<(NEDGE + 255) / 256, 256, 0, stream>>>(src, dst, row_start, cursor, esrc, NEDGE);

    dim3 ggrid((NNODES + BM - 1) / BM, DIM / BN);
    const int aggBlocks = (NNODES * 64 + 255) / 256;   // one wave per node

    // ---- layer 1 ----
    aggregate<<<aggBlocks, 256, 0, stream>>>(esrc, row_start, cnt, x, agg);
    sage_gemm<<<ggrid, 256, 0, stream>>>(agg, x, Wl1, Wr1, b1, h1, NNODES, 1);

    // ---- layer 2 ----
    aggregate<<<aggBlocks, 256, 0, stream>>>(esrc, row_start, cnt, h1, agg);
    sage_gemm<<<ggrid, 256, 0, stream>>>(agg, h1, Wl2, Wr2, b2, h2, NNODES, 1);

    // ---- layer 3 ----
    aggregate<<<aggBlocks, 256, 0, stream>>>(esrc, row_start, cnt, h2, agg);
    sage_gemm<<<ggrid, 256, 0, stream>>>(agg, h2, Wl3, Wr3, b3, (float*)d_out, NNODES, 0);
}

// Round 4
// 788.331 us; speedup vs baseline: 5.7200x; 2.1670x over previous
//
#include <hip/hip_runtime.h>

typedef unsigned short ushort_t;
typedef __attribute__((ext_vector_type(8))) short bf16x8;
typedef __attribute__((ext_vector_type(4))) float f32x4;

#define NNODES 100000
#define DIM    256
#define NEDGE  300000
#define KTOT   512          // virtual K = [agg | xin]
#define KSTEPS 16           // BK = 32
#define BROWS  128          // rows per block (4 waves x 2 row-tiles x 16)
#define NTILES 16           // 256 / 16 column tiles
#define LDSTRIDE 40         // ushorts per 32-k row (16B-aligned rows, odd-ish bank spread)
#define PLANE  (256 * LDSTRIDE)   // ushorts per (hi|lo) plane

// ================= CSR build (counting sort by dst) =================

__global__ void count_kernel(const int* __restrict__ dst, int* __restrict__ cnt, int E) {
    int e = blockIdx.x * blockDim.x + threadIdx.x;
    if (e < E) atomicAdd(&cnt[dst[e]], 1);
}

__global__ void scan1(const int* __restrict__ cnt, int* __restrict__ partial, int n) {
    __shared__ int s[256];
    int i = blockIdx.x * 256 + threadIdx.x;
    s[threadIdx.x] = (i < n) ? cnt[i] : 0;
    __syncthreads();
    for (int off = 128; off > 0; off >>= 1) {
        if (threadIdx.x < off) s[threadIdx.x] += s[threadIdx.x + off];
        __syncthreads();
    }
    if (threadIdx.x == 0) partial[blockIdx.x] = s[0];
}

__global__ void scan2(int* __restrict__ partial, int nb) {
    __shared__ int s[512];
    int t = threadIdx.x;
    int orig = (t < nb) ? partial[t] : 0;
    s[t] = orig;
    __syncthreads();
    for (int off = 1; off < 512; off <<= 1) {
        int v = (t >= off) ? s[t - off] : 0;
        __syncthreads();
        s[t] += v;
        __syncthreads();
    }
    if (t < nb) partial[t] = s[t] - orig;  // exclusive
}

__global__ void scan3(const int* __restrict__ cnt, const int* __restrict__ partial,
                      int* __restrict__ row_start, int n) {
    __shared__ int s[256];
    int i = blockIdx.x * 256 + threadIdx.x;
    int v = (i < n) ? cnt[i] : 0;
    s[threadIdx.x] = v;
    __syncthreads();
    for (int off = 1; off < 256; off <<= 1) {
        int t = (threadIdx.x >= off) ? s[threadIdx.x - off] : 0;
        __syncthreads();
        s[threadIdx.x] += t;
        __syncthreads();
    }
    if (i < n) row_start[i] = partial[blockIdx.x] + s[threadIdx.x] - v;
}

__global__ void fill_csr(const int* __restrict__ src, const int* __restrict__ dst,
                         const int* __restrict__ row_start, int* __restrict__ cursor,
                         int* __restrict__ esrc, int E) {
    int e = blockIdx.x * blockDim.x + threadIdx.x;
    if (e < E) {
        int d = dst[e];
        int pos = row_start[d] + atomicAdd(&cursor[d], 1);
        esrc[pos] = src[e];
    }
}

// ================= aggregation: one wave per node =================
__global__ __launch_bounds__(256) void aggregate(
    const int* __restrict__ esrc, const int* __restrict__ row_start,
    const int* __restrict__ cnt, const float* __restrict__ x, float* __restrict__ agg)
{
    int node = (blockIdx.x * blockDim.x + threadIdx.x) >> 6;
    int lane = threadIdx.x & 63;
    if (node >= NNODES) return;
    int start = row_start[node];
    int c = cnt[node];
    float4 acc = make_float4(0.f, 0.f, 0.f, 0.f);
    for (int i = 0; i < c; i++) {
        int s = esrc[start + i];
        float4 v = ((const float4*)(x + (size_t)s * DIM))[lane];
        acc.x += v.x; acc.y += v.y; acc.z += v.z; acc.w += v.w;
    }
    float inv = (c > 0) ? 1.0f / (float)c : 0.0f;
    ((float4*)(agg + (size_t)node * DIM))[lane] =
        make_float4(acc.x * inv, acc.y * inv, acc.z * inv, acc.w * inv);
}

// ========== weight split: B[n][k] = (k<256 ? Wl : Wr) -> hi/lo bf16 planes ==========
__global__ void conv_weights(const float* __restrict__ Wl, const float* __restrict__ Wr,
                             ushort_t* __restrict__ Bh, ushort_t* __restrict__ Bl) {
    int idx = blockIdx.x * 256 + threadIdx.x;
    if (idx >= 256 * KTOT) return;
    int n = idx >> 9, k = idx & 511;
    float v = (k < DIM) ? Wl[n * DIM + k] : Wr[n * DIM + (k - DIM)];
    unsigned u = __float_as_uint(v);
    unsigned hi = u & 0xFFFF0000u;
    float lo = v - __uint_as_float(hi);
    Bh[idx] = (ushort_t)(u >> 16);
    Bl[idx] = (ushort_t)(__float_as_uint(lo) >> 16);
}

// ================= helpers (plain free functions — no lambdas, no unions) =================

__device__ __forceinline__ void stage_b(const ushort_t* __restrict__ Bh,
                                        const ushort_t* __restrict__ Bl,
                                        ushort_t* buf, int tid, int k0) {
    #pragma unroll
    for (int i = 0; i < 8; i++) {
        int c = tid + i * 256;            // 0..2047 chunks of 8 ushorts
        int plane = c >> 10;
        int cc = c & 1023;
        int n  = cc >> 2;
        int k8 = (cc & 3) * 8;
        const ushort_t* src = (plane ? Bl : Bh) + n * KTOT + k0 + k8;
        *(bf16x8*)(buf + plane * PLANE + n * LDSTRIDE + k8) = *(const bf16x8*)src;
    }
}

__device__ __forceinline__ void load_a(const float* __restrict__ base, int row0, int row1,
                                       int kk, int M, float* va /*16 floats*/) {
    if (row0 < M) {
        *(float4*)(va + 0) = *(const float4*)(base + (size_t)row0 * DIM + kk);
        *(float4*)(va + 4) = *(const float4*)(base + (size_t)row0 * DIM + kk + 4);
    } else {
        *(float4*)(va + 0) = make_float4(0.f, 0.f, 0.f, 0.f);
        *(float4*)(va + 4) = make_float4(0.f, 0.f, 0.f, 0.f);
    }
    if (row1 < M) {
        *(float4*)(va + 8)  = *(const float4*)(base + (size_t)row1 * DIM + kk);
        *(float4*)(va + 12) = *(const float4*)(base + (size_t)row1 * DIM + kk + 4);
    } else {
        *(float4*)(va + 8)  = make_float4(0.f, 0.f, 0.f, 0.f);
        *(float4*)(va + 12) = make_float4(0.f, 0.f, 0.f, 0.f);
    }
}

__device__ __forceinline__ void split8(const float* __restrict__ a, bf16x8& h, bf16x8& l) {
    #pragma unroll
    for (int i = 0; i < 8; i++) {
        float x = a[i];
        unsigned u = __float_as_uint(x);
        unsigned hb = u & 0xFFFF0000u;
        h[i] = (short)(u >> 16);
        float lo = x - __uint_as_float(hb);
        l[i] = (short)(__float_as_uint(lo) >> 16);
    }
}

// ================= MFMA GEMM: out = [agg|xin] @ B^T + bias (split-bf16, fp32 acc) =================
__global__ __launch_bounds__(256, 2) void sage_gemm_mfma(
    const float* __restrict__ agg, const float* __restrict__ xin,
    const ushort_t* __restrict__ Bh, const ushort_t* __restrict__ Bl,
    const float* __restrict__ bias, float* __restrict__ out, int M, int do_relu)
{
    __shared__ __align__(16) ushort_t Bs[2][2 * PLANE];

    const int tid  = threadIdx.x;
    const int lane = tid & 63;
    const int wave = tid >> 6;
    const int lrow = lane & 15;
    const int quad = lane >> 4;

    const int rowbase = blockIdx.x * BROWS + wave * 32;
    const int arow0 = rowbase + lrow;
    const int arow1 = rowbase + 16 + lrow;
    const int kq    = quad * 8;

    f32x4 acc[2][NTILES];
    #pragma unroll
    for (int i = 0; i < 2; i++)
        #pragma unroll
        for (int j = 0; j < NTILES; j++)
            acc[i][j] = (f32x4){0.f, 0.f, 0.f, 0.f};

    float aC[16], aN[16];
    stage_b(Bh, Bl, &Bs[0][0], tid, 0);
    load_a(agg, arow0, arow1, kq, M, aC);

    for (int ks = 0; ks < KSTEPS; ks++) {
        __syncthreads();
        if (ks + 1 < KSTEPS) {
            int ks1 = ks + 1;
            stage_b(Bh, Bl, &Bs[ks1 & 1][0], tid, ks1 * 32);
            const float* base = (ks1 < 8) ? agg : xin;
            int kk = ((ks1 < 8) ? ks1 * 32 : (ks1 - 8) * 32) + kq;
            load_a(base, arow0, arow1, kk, M, aN);
        }

        bf16x8 ah0, al0, ah1, al1;
        split8(aC + 0, ah0, al0);
        split8(aC + 8, ah1, al1);

        const ushort_t* bp = &Bs[ks & 1][0];
        #pragma unroll
        for (int ct = 0; ct < NTILES; ct++) {
            const int n = ct * 16 + lrow;
            const bf16x8 bh = *(const bf16x8*)(bp + n * LDSTRIDE + kq);
            const bf16x8 bl = *(const bf16x8*)(bp + PLANE + n * LDSTRIDE + kq);
            acc[0][ct] = __builtin_amdgcn_mfma_f32_16x16x32_bf16(ah0, bh, acc[0][ct], 0, 0, 0);
            acc[1][ct] = __builtin_amdgcn_mfma_f32_16x16x32_bf16(ah1, bh, acc[1][ct], 0, 0, 0);
            acc[0][ct] = __builtin_amdgcn_mfma_f32_16x16x32_bf16(al0, bh, acc[0][ct], 0, 0, 0);
            acc[1][ct] = __builtin_amdgcn_mfma_f32_16x16x32_bf16(al1, bh, acc[1][ct], 0, 0, 0);
            acc[0][ct] = __builtin_amdgcn_mfma_f32_16x16x32_bf16(ah0, bl, acc[0][ct], 0, 0, 0);
            acc[1][ct] = __builtin_amdgcn_mfma_f32_16x16x32_bf16(ah1, bl, acc[1][ct], 0, 0, 0);
        }

        if (ks + 1 < KSTEPS) {
            #pragma unroll
            for (int i = 0; i < 16; i++) aC[i] = aN[i];
        }
    }

    // ---- epilogue: bias + optional relu; C layout: col=lane&15, row=quad*4+reg ----
    #pragma unroll
    for (int ct = 0; ct < NTILES; ct++) {
        const int col = ct * 16 + lrow;
        const float bv = bias[col];
        #pragma unroll
        for (int rt = 0; rt < 2; rt++) {
            const int row = rowbase + rt * 16 + quad * 4;
            #pragma unroll
            for (int r = 0; r < 4; r++) {
                if (row + r < M) {
                    float v = acc[rt][ct][r] + bv;
                    if (do_relu) v = fmaxf(v, 0.f);
                    out[(size_t)(row + r) * DIM + col] = v;
                }
            }
        }
    }
}

extern "C" void kernel_launch(void* const* d_in, const int* in_sizes, int n_in,
                              void* d_out, int out_size, void* d_ws, size_t ws_size,
                              hipStream_t stream) {
    const int*   edge = (const int*)d_in[0];
    const int*   src  = edge;
    const int*   dst  = edge + NEDGE;
    const float* x    = (const float*)d_in[1];
    const float* Wl1  = (const float*)d_in[2];
    const float* Wr1  = (const float*)d_in[3];
    const float* b1   = (const float*)d_in[4];
    const float* Wl2  = (const float*)d_in[5];
    const float* Wr2  = (const float*)d_in[6];
    const float* b2   = (const float*)d_in[7];
    const float* Wl3  = (const float*)d_in[8];
    const float* Wr3  = (const float*)d_in[9];
    const float* b3   = (const float*)d_in[10];

    const size_t feat = (size_t)NNODES * DIM;
    float*    agg       = (float*)d_ws;
    float*    h2        = agg + feat;
    int*      cnt       = (int*)(h2 + feat);
    int*      row_start = cnt + NNODES;
    int*      cursor    = row_start + NNODES;
    int*      partial   = cursor + NNODES;            // 512
    int*      esrc      = partial + 512;              // NEDGE
    ushort_t* Bh        = (ushort_t*)(esrc + NEDGE);  // 256*512 ushorts (per-layer, reused)
    ushort_t* Bl        = Bh + 256 * KTOT;
    float*    h1        = (float*)d_out;   // layer-1 out in d_out; rewritten by layer 3

    const int nScanBlocks = (NNODES + 255) / 256;

    // ---- CSR build (edge structure shared by all 3 layers) ----
    hipMemsetAsync(cnt, 0, NNODES * sizeof(int), stream);
    hipMemsetAsync(cursor, 0, NNODES * sizeof(int), stream);
    count_kernel<<<(NEDGE + 255) / 256, 256, 0, stream>>>(dst, cnt, NEDGE);
    scan1<<<nScanBlocks, 256, 0, stream>>>(cnt, partial, NNODES);
    scan2<<<1, 512, 0, stream>>>(partial, nScanBlocks);
    scan3<<<nScanBlocks, 256, 0, stream>>>(cnt, partial, row_start, NNODES);
    fill_csr<<<(NEDGE + 255) / 256, 256, 0, stream>>>(src, dst, row_start, cursor, esrc, NEDGE);

    const int aggBlocks  = (NNODES * 64 + 255) / 256;
    const int gemmBlocks = (NNODES + BROWS - 1) / BROWS;
    const int convBlocks = (256 * KTOT + 255) / 256;

    // ---- layer 1 ----
    conv_weights<<<convBlocks, 256, 0, stream>>>(Wl1, Wr1, Bh, Bl);
    aggregate<<<aggBlocks, 256, 0, stream>>>(esrc, row_start, cnt, x, agg);
    sage_gemm_mfma<<<gemmBlocks, 256, 0, stream>>>(agg, x, Bh, Bl, b1, h1, NNODES, 1);

    // ---- layer 2 ----
    conv_weights<<<convBlocks, 256, 0, stream>>>(Wl2, Wr2, Bh, Bl);
    aggregate<<<aggBlocks, 256, 0, stream>>>(esrc, row_start, cnt, h1, agg);
    sage_gemm_mfma<<<gemmBlocks, 256, 0, stream>>>(agg, h1, Bh, Bl, b2, h2, NNODES, 1);

    // ---- layer 3 ----
    conv_weights<<<convBlocks, 256, 0, stream>>>(Wl3, Wr3, Bh, Bl);
    aggregate<<<aggBlocks, 256, 0, stream>>>(esrc, row_start, cnt, h2, agg);
    sage_gemm_mfma<<<gemmBlocks, 256, 0, stream>>>(agg, h2, Bh, Bl, b3, (float*)d_out, NNODES, 0);
}

// Round 5
// 774.112 us; speedup vs baseline: 5.8250x; 1.0184x over previous
//
#include <hip/hip_runtime.h>

typedef unsigned short ushort_t;
typedef __attribute__((ext_vector_type(8))) short bf16x8;
typedef __attribute__((ext_vector_type(4))) float f32x4;

#define NNODES 100000
#define DIM    256
#define NEDGE  300000
#define KTOT   512          // virtual K = [agg | xin]
#define KSTEPS 16           // BK = 32
#define BROWS  128          // rows per block (4 waves x 2 row-tiles x 16)
#define NTILES 16           // 256 / 16 column tiles
#define SLICE  16384        // ushorts per 32-k slice: 2 planes x 256 n x 32 k
// slice layout (ushort units): plane*8192 + ct*512 + quad*128 + nn*8 + j
//   => chunk c = plane*1024 + ct*64 + (quad*16 + nn); lane reads chunk = tilebase + lane

// ================= CSR build (counting sort by dst) =================

__global__ void count_kernel(const int* __restrict__ dst, int* __restrict__ cnt, int E) {
    int e = blockIdx.x * blockDim.x + threadIdx.x;
    if (e < E) atomicAdd(&cnt[dst[e]], 1);
}

__global__ void scan1(const int* __restrict__ cnt, int* __restrict__ partial, int n) {
    __shared__ int s[256];
    int i = blockIdx.x * 256 + threadIdx.x;
    s[threadIdx.x] = (i < n) ? cnt[i] : 0;
    __syncthreads();
    for (int off = 128; off > 0; off >>= 1) {
        if (threadIdx.x < off) s[threadIdx.x] += s[threadIdx.x + off];
        __syncthreads();
    }
    if (threadIdx.x == 0) partial[blockIdx.x] = s[0];
}

__global__ void scan2(int* __restrict__ partial, int nb) {
    __shared__ int s[512];
    int t = threadIdx.x;
    int orig = (t < nb) ? partial[t] : 0;
    s[t] = orig;
    __syncthreads();
    for (int off = 1; off < 512; off <<= 1) {
        int v = (t >= off) ? s[t - off] : 0;
        __syncthreads();
        s[t] += v;
        __syncthreads();
    }
    if (t < nb) partial[t] = s[t] - orig;  // exclusive
}

__global__ void scan3(const int* __restrict__ cnt, const int* __restrict__ partial,
                      int* __restrict__ row_start, int n) {
    __shared__ int s[256];
    int i = blockIdx.x * 256 + threadIdx.x;
    int v = (i < n) ? cnt[i] : 0;
    s[threadIdx.x] = v;
    __syncthreads();
    for (int off = 1; off < 256; off <<= 1) {
        int t = (threadIdx.x >= off) ? s[threadIdx.x - off] : 0;
        __syncthreads();
        s[threadIdx.x] += t;
        __syncthreads();
    }
    if (i < n) row_start[i] = partial[blockIdx.x] + s[threadIdx.x] - v;
}

__global__ void fill_csr(const int* __restrict__ src, const int* __restrict__ dst,
                         const int* __restrict__ row_start, int* __restrict__ cursor,
                         int* __restrict__ esrc, int E) {
    int e = blockIdx.x * blockDim.x + threadIdx.x;
    if (e < E) {
        int d = dst[e];
        int pos = row_start[d] + atomicAdd(&cursor[d], 1);
        esrc[pos] = src[e];
    }
}

// ================= aggregation: one wave per node =================
__global__ __launch_bounds__(256) void aggregate(
    const int* __restrict__ esrc, const int* __restrict__ row_start,
    const int* __restrict__ cnt, const float* __restrict__ x, float* __restrict__ agg)
{
    int node = (blockIdx.x * blockDim.x + threadIdx.x) >> 6;
    int lane = threadIdx.x & 63;
    if (node >= NNODES) return;
    int start = row_start[node];
    int c = cnt[node];
    float4 acc = make_float4(0.f, 0.f, 0.f, 0.f);
    for (int i = 0; i < c; i++) {
        int s = esrc[start + i];
        float4 v = ((const float4*)(x + (size_t)s * DIM))[lane];
        acc.x += v.x; acc.y += v.y; acc.z += v.z; acc.w += v.w;
    }
    float inv = (c > 0) ? 1.0f / (float)c : 0.0f;
    ((float4*)(agg + (size_t)node * DIM))[lane] =
        make_float4(acc.x * inv, acc.y * inv, acc.z * inv, acc.w * inv);
}

// ========== weight split + swizzle into MFMA-fragment/LDS-linear order ==========
__global__ void conv_weights(const float* __restrict__ Wl, const float* __restrict__ Wr,
                             ushort_t* __restrict__ Bsw) {
    int idx = blockIdx.x * 256 + threadIdx.x;      // n*512 + k
    if (idx >= 256 * KTOT) return;
    int n = idx >> 9, k = idx & 511;
    float v = (k < DIM) ? Wl[n * DIM + k] : Wr[n * DIM + (k - DIM)];
    unsigned u = __float_as_uint(v);
    unsigned hb = u & 0xFFFF0000u;
    float lo = v - __uint_as_float(hb);
    int ks = k >> 5, q = (k >> 3) & 3, j = k & 7;
    int ct = n >> 4, nn = n & 15;
    int base = ks * SLICE + ct * 512 + q * 128 + nn * 8 + j;
    Bsw[base]        = (ushort_t)(u >> 16);                      // hi plane
    Bsw[base + 8192] = (ushort_t)(__float_as_uint(lo) >> 16);    // lo plane
}

// ================= helpers =================

__device__ __forceinline__ void stage_b(const ushort_t* __restrict__ slice,
                                        ushort_t* buf, int tid) {
    #pragma unroll
    for (int i = 0; i < 8; i++) {
        int c = tid + i * 256;                     // 2048 chunks of 8 ushorts (16 B)
        *(bf16x8*)(buf + c * 8) = *(const bf16x8*)(slice + c * 8);
    }
}

__device__ __forceinline__ void load_a(const float* __restrict__ base, int row0, int row1,
                                       int kk, int M, float* va /*16 floats*/) {
    if (row0 < M) {
        *(float4*)(va + 0) = *(const float4*)(base + (size_t)row0 * DIM + kk);
        *(float4*)(va + 4) = *(const float4*)(base + (size_t)row0 * DIM + kk + 4);
    } else {
        *(float4*)(va + 0) = make_float4(0.f, 0.f, 0.f, 0.f);
        *(float4*)(va + 4) = make_float4(0.f, 0.f, 0.f, 0.f);
    }
    if (row1 < M) {
        *(float4*)(va + 8)  = *(const float4*)(base + (size_t)row1 * DIM + kk);
        *(float4*)(va + 12) = *(const float4*)(base + (size_t)row1 * DIM + kk + 4);
    } else {
        *(float4*)(va + 8)  = make_float4(0.f, 0.f, 0.f, 0.f);
        *(float4*)(va + 12) = make_float4(0.f, 0.f, 0.f, 0.f);
    }
}

__device__ __forceinline__ void split8(const float* __restrict__ a, bf16x8& h, bf16x8& l) {
    #pragma unroll
    for (int i = 0; i < 8; i++) {
        float x = a[i];
        unsigned u = __float_as_uint(x);
        unsigned hb = u & 0xFFFF0000u;
        h[i] = (short)(u >> 16);
        float lo = x - __uint_as_float(hb);
        l[i] = (short)(__float_as_uint(lo) >> 16);
    }
}

// ================= MFMA GEMM: out = [agg|xin] @ B^T + bias (split-bf16, fp32 acc) =================
__global__ __launch_bounds__(256, 2) void sage_gemm_mfma(
    const float* __restrict__ agg, const float* __restrict__ xin,
    const ushort_t* __restrict__ Bsw,
    const float* __restrict__ bias, float* __restrict__ out, int M, int do_relu)
{
    __shared__ __align__(16) ushort_t Bs[2][SLICE];

    const int tid  = threadIdx.x;
    const int lane = tid & 63;
    const int wave = tid >> 6;
    const int lrow = lane & 15;
    const int quad = lane >> 4;

    const int rowbase = blockIdx.x * BROWS + wave * 32;
    const int arow0 = rowbase + lrow;
    const int arow1 = rowbase + 16 + lrow;
    const int kq    = quad * 8;
    const int fragoff = quad * 128 + lrow * 8;     // lane-contiguous: = lane*8 ushorts

    f32x4 acc[2][NTILES];
    #pragma unroll
    for (int i = 0; i < 2; i++)
        #pragma unroll
        for (int j = 0; j < NTILES; j++)
            acc[i][j] = (f32x4){0.f, 0.f, 0.f, 0.f};

    float aC[16], aN[16];
    stage_b(Bsw, &Bs[0][0], tid);
    load_a(agg, arow0, arow1, kq, M, aC);

    for (int ks = 0; ks < KSTEPS; ks++) {
        __syncthreads();
        if (ks + 1 < KSTEPS) {
            int ks1 = ks + 1;
            stage_b(Bsw + ks1 * SLICE, &Bs[ks1 & 1][0], tid);
            const float* base = (ks1 < 8) ? agg : xin;
            int kk = ((ks1 < 8) ? ks1 * 32 : (ks1 - 8) * 32) + kq;
            load_a(base, arow0, arow1, kk, M, aN);
        }

        bf16x8 ah0, al0, ah1, al1;
        split8(aC + 0, ah0, al0);
        split8(aC + 8, ah1, al1);

        const ushort_t* bp = &Bs[ks & 1][0];
        #pragma unroll
        for (int ct = 0; ct < NTILES; ct++) {
            const bf16x8 bh = *(const bf16x8*)(bp + ct * 512 + fragoff);
            const bf16x8 bl = *(const bf16x8*)(bp + 8192 + ct * 512 + fragoff);
            acc[0][ct] = __builtin_amdgcn_mfma_f32_16x16x32_bf16(ah0, bh, acc[0][ct], 0, 0, 0);
            acc[1][ct] = __builtin_amdgcn_mfma_f32_16x16x32_bf16(ah1, bh, acc[1][ct], 0, 0, 0);
            acc[0][ct] = __builtin_amdgcn_mfma_f32_16x16x32_bf16(al0, bh, acc[0][ct], 0, 0, 0);
            acc[1][ct] = __builtin_amdgcn_mfma_f32_16x16x32_bf16(al1, bh, acc[1][ct], 0, 0, 0);
            acc[0][ct] = __builtin_amdgcn_mfma_f32_16x16x32_bf16(ah0, bl, acc[0][ct], 0, 0, 0);
            acc[1][ct] = __builtin_amdgcn_mfma_f32_16x16x32_bf16(ah1, bl, acc[1][ct], 0, 0, 0);
        }

        if (ks + 1 < KSTEPS) {
            #pragma unroll
            for (int i = 0; i < 16; i++) aC[i] = aN[i];
        }
    }

    // ---- epilogue: bias + optional relu; C layout: col=lane&15, row=quad*4+reg ----
    #pragma unroll
    for (int ct = 0; ct < NTILES; ct++) {
        const int col = ct * 16 + lrow;
        const float bv = bias[col];
        #pragma unroll
        for (int rt = 0; rt < 2; rt++) {
            const int row = rowbase + rt * 16 + quad * 4;
            #pragma unroll
            for (int r = 0; r < 4; r++) {
                if (row + r < M) {
                    float v = acc[rt][ct][r] + bv;
                    if (do_relu) v = fmaxf(v, 0.f);
                    out[(size_t)(row + r) * DIM + col] = v;
                }
            }
        }
    }
}

extern "C" void kernel_launch(void* const* d_in, const int* in_sizes, int n_in,
                              void* d_out, int out_size, void* d_ws, size_t ws_size,
                              hipStream_t stream) {
    const int*   edge = (const int*)d_in[0];
    const int*   src  = edge;
    const int*   dst  = edge + NEDGE;
    const float* x    = (const float*)d_in[1];
    const float* Wl1  = (const float*)d_in[2];
    const float* Wr1  = (const float*)d_in[3];
    const float* b1   = (const float*)d_in[4];
    const float* Wl2  = (const float*)d_in[5];
    const float* Wr2  = (const float*)d_in[6];
    const float* b2   = (const float*)d_in[7];
    const float* Wl3  = (const float*)d_in[8];
    const float* Wr3  = (const float*)d_in[9];
    const float* b3   = (const float*)d_in[10];

    const size_t feat = (size_t)NNODES * DIM;
    float*    agg       = (float*)d_ws;
    float*    h2        = agg + feat;
    int*      cnt       = (int*)(h2 + feat);
    int*      row_start = cnt + NNODES;
    int*      cursor    = row_start + NNODES;
    int*      partial   = cursor + NNODES;            // 512
    int*      esrc      = partial + 512;              // NEDGE
    ushort_t* Bsw       = (ushort_t*)(esrc + NEDGE);  // KSTEPS*SLICE ushorts (512 KB)
    float*    h1        = (float*)d_out;   // layer-1 out in d_out; rewritten by layer 3

    const int nScanBlocks = (NNODES + 255) / 256;

    // ---- CSR build (edge structure shared by all 3 layers) ----
    hipMemsetAsync(cnt, 0, NNODES * sizeof(int), stream);
    hipMemsetAsync(cursor, 0, NNODES * sizeof(int), stream);
    count_kernel<<<(NEDGE + 255) / 256, 256, 0, stream>>>(dst, cnt, NEDGE);
    scan1<<<nScanBlocks, 256, 0, stream>>>(cnt, partial, NNODES);
    scan2<<<1, 512, 0, stream>>>(partial, nScanBlocks);
    scan3<<<nScanBlocks, 256, 0, stream>>>(cnt, partial, row_start, NNODES);
    fill_csr<<<(NEDGE + 255) / 256, 256, 0, stream>>>(src, dst, row_start, cursor, esrc, NEDGE);

    const int aggBlocks  = (NNODES * 64 + 255) / 256;
    const int gemmBlocks = (NNODES + BROWS - 1) / BROWS;
    const int convBlocks = (256 * KTOT + 255) / 256;

    // ---- layer 1 ----
    conv_weights<<<convBlocks, 256, 0, stream>>>(Wl1, Wr1, Bsw);
    aggregate<<<aggBlocks, 256, 0, stream>>>(esrc, row_start, cnt, x, agg);
    sage_gemm_mfma<<<gemmBlocks, 256, 0, stream>>>(agg, x, Bsw, b1, h1, NNODES, 1);

    // ---- layer 2 ----
    conv_weights<<<convBlocks, 256, 0, stream>>>(Wl2, Wr2, Bsw);
    aggregate<<<aggBlocks, 256, 0, stream>>>(esrc, row_start, cnt, h1, agg);
    sage_gemm_mfma<<<gemmBlocks, 256, 0, stream>>>(agg, h1, Bsw, b2, h2, NNODES, 1);

    // ---- layer 3 ----
    conv_weights<<<convBlocks, 256, 0, stream>>>(Wl3, Wr3, Bsw);
    aggregate<<<aggBlocks, 256, 0, stream>>>(esrc, row_start, cnt, h2, agg);
    sage_gemm_mfma<<<gemmBlocks, 256, 0, stream>>>(agg, h2, Bsw, b3, (float*)d_out, NNODES, 0);
}